// Round 1
// baseline (126.067 us; speedup 1.0000x reference)
//
#include <hip/hip_runtime.h>
#include <stdint.h>

// Problem constants (fixed by setup_inputs: B=4, N_obj=8, N_v=2048)
#define NPTS 2048
#define KNN  16
#define AK   64
#define TPB  256
#define FPT  (NPTS / TPB)   // knn staging: 8 points per thread
#define KPL  (NPTS / 64)    // 32 points per lane (one wave per anchor)
#define FW   (NPTS / 64)    // fps: 32 points per lane (one wave per object)

typedef unsigned long long u64;
typedef unsigned int u32;
#define UMAX 0xFFFFFFFFFFFFFFFFull

// Exact float32 helpers (no FMA contraction -> match reference bitwise)
__device__ __forceinline__ float sq3(float x, float y, float z) {
    return __fadd_rn(__fadd_rn(__fmul_rn(x, x), __fmul_rn(y, y)), __fmul_rn(z, z));
}

// ---------------------------------------------------------------------------
// 64-lane butterfly reductions on u64 keys, ALL-VALU (no LDS/ds_bpermute).
// Stages 1,2,4,8: DPP permutations. quad_perm(1,0,3,2)=0xB1 is xor1;
// quad_perm(2,3,0,1)=0x4E is xor2; row_half_mirror(0x141)=xor4 once quads
// uniform; row_mirror(0x140)=xor8 once 8-groups uniform.
// Stages 16,32: gfx950 v_permlane16_swap / v_permlane32_swap with self:
//   permlane16_swap(k,k): dst={r0,r0,r2,r2}, src={r1,r1,r3,r3} (16-lane rows)
//   permlane32_swap(k,k): dst={r0,r1,r0,r1}, src={r2,r3,r2,r3}
// Reducing with BOTH results realizes the xor exchange (self-compares are
// no-ops). Guarded by __has_builtin with ds_bpermute shfl fallback.
// ---------------------------------------------------------------------------
template <int CTRL>
__device__ __forceinline__ u64 dpp64(u64 k) {
    const int lo = __builtin_amdgcn_update_dpp((int)(u32)k, (int)(u32)k,
                                               CTRL, 0xF, 0xF, false);
    const int hi = __builtin_amdgcn_update_dpp((int)(u32)(k >> 32),
                                               (int)(u32)(k >> 32),
                                               CTRL, 0xF, 0xF, false);
    return ((u64)(u32)hi << 32) | (u32)lo;
}

__device__ __forceinline__ void swap16_pair(u64 k, u64& a, u64& b) {
#if __has_builtin(__builtin_amdgcn_permlane16_swap)
    const u32 lo = (u32)k, hi = (u32)(k >> 32);
    const auto rl = __builtin_amdgcn_permlane16_swap(lo, lo, false, false);
    const auto rh = __builtin_amdgcn_permlane16_swap(hi, hi, false, false);
    a = ((u64)(u32)rh[0] << 32) | (u32)rl[0];
    b = ((u64)(u32)rh[1] << 32) | (u32)rl[1];
#else
    a = (u64)__shfl_xor((long long)k, 16, 64);
    b = a;
#endif
}

__device__ __forceinline__ void swap32_pair(u64 k, u64& a, u64& b) {
#if __has_builtin(__builtin_amdgcn_permlane32_swap)
    const u32 lo = (u32)k, hi = (u32)(k >> 32);
    const auto rl = __builtin_amdgcn_permlane32_swap(lo, lo, false, false);
    const auto rh = __builtin_amdgcn_permlane32_swap(hi, hi, false, false);
    a = ((u64)(u32)rh[0] << 32) | (u32)rl[0];
    b = ((u64)(u32)rh[1] << 32) | (u32)rl[1];
#else
    a = (u64)__shfl_xor((long long)k, 32, 64);
    b = a;
#endif
}

__device__ __forceinline__ u64 wave_max64(u64 k) {
    u64 o, a, b;
    o = dpp64<0xB1>(k);  if (o > k) k = o;
    o = dpp64<0x4E>(k);  if (o > k) k = o;
    o = dpp64<0x141>(k); if (o > k) k = o;
    o = dpp64<0x140>(k); if (o > k) k = o;
    swap16_pair(k, a, b); if (a > k) k = a; if (b > k) k = b;
    swap32_pair(k, a, b); if (a > k) k = a; if (b > k) k = b;
    return k;
}

__device__ __forceinline__ u64 wave_min64(u64 k) {
    u64 o, a, b;
    o = dpp64<0xB1>(k);  if (o < k) k = o;
    o = dpp64<0x4E>(k);  if (o < k) k = o;
    o = dpp64<0x141>(k); if (o < k) k = o;
    o = dpp64<0x140>(k); if (o < k) k = o;
    swap16_pair(k, a, b); if (a < k) k = a; if (b < k) k = b;
    swap32_pair(k, a, b); if (a < k) k = a; if (b < k) k = b;
    return k;
}

// ---------------------------------------------------------------------------
// Kernel 1: farthest-point sampling, ONE WAVE per object (32 blocks x 64).
// Rationale: the 4-wave version paid ~900 cyc/step for the cross-wave merge
// (LDS round trips + __syncthreads, whose vmcnt(0) drain includes the
// per-step anchor store). Single wave: no barrier at all, anchor stores are
// fire-and-forget, butterfly is all-VALU, winner coords come from one
// same-address (broadcast) ds_read_b128. Scan widens to 32 pts/lane but the
// whole step chain is ~1.1-1.2k cyc vs the measured 1.6k.
// ---------------------------------------------------------------------------
__global__ __launch_bounds__(64) void fps_kernel(const float* __restrict__ pos,
                                                 int* __restrict__ anchors) {
    const int obj = blockIdx.x;
    const int lane = threadIdx.x & 63;

    __shared__ float4 sP[NPTS];   // (x,y,z,0) winner-lookup tile, 32 KB

    const float* pts = pos + (size_t)obj * NPTS * 3;
    float px[FW], py[FW], pz[FW], mind[FW];
    #pragma unroll
    for (int i = 0; i < FW; i++) {
        const int j = lane + i * 64;
        const float x = pts[j * 3 + 0];
        const float y = pts[j * 3 + 1];
        const float z = pts[j * 3 + 2];
        px[i] = x; py[i] = y; pz[i] = z;
        sP[j] = make_float4(x, y, z, 0.f);
    }
    if (lane == 0) anchors[obj * AK + 0] = 0;

    // seed: distance to point 0 (exact, like lax.scan's d0)
    const float ax0 = __shfl(px[0], 0, 64);
    const float ay0 = __shfl(py[0], 0, 64);
    const float az0 = __shfl(pz[0], 0, 64);
    float bv = -1.0f; u32 bj = 0;
    #pragma unroll
    for (int i = 0; i < FW; i++) {
        const float d2 = sq3(__fsub_rn(px[i], ax0), __fsub_rn(py[i], ay0),
                             __fsub_rn(pz[i], az0));
        mind[i] = d2;
        if (d2 > bv) { bv = d2; bj = (u32)(lane + i * 64); }  // strict: smallest j
    }
    // mind >= 0 -> float bits order-monotonic; ~j -> smaller j wins ties
    u64 key = ((u64)__float_as_uint(bv) << 32) | (u32)(~bj);

    #pragma unroll 1
    for (int s = 1; s < AK; s++) {
        const u64 wk = wave_max64(key);           // all lanes hold winner
        const int widx = (int)(~(u32)wk);
        if (lane == 0) anchors[obj * AK + s] = widx;   // no drain: no barrier
        if (s == AK - 1) break;

        const float4 c = sP[widx];                // broadcast read, conflict-free

        // fused min-update + argmax scan (exact direct (p-b)^2 like lax.scan)
        float nbv = -1.0f; u32 nbj = 0;
        #pragma unroll
        for (int i = 0; i < FW; i++) {
            const float d2 = sq3(__fsub_rn(px[i], c.x), __fsub_rn(py[i], c.y),
                                 __fsub_rn(pz[i], c.z));
            const float nm = fminf(mind[i], d2);
            mind[i] = nm;
            if (nm > nbv) { nbv = nm; nbj = (u32)(lane + i * 64); }
        }
        key = ((u64)__float_as_uint(nbv) << 32) | (u32)(~nbj);
    }
}

// ---------------------------------------------------------------------------
// Kernel 2: KNN dist-vec + gather + concat. ONE WAVE per anchor, 4 anchors
// per block. Changes vs previous version:
//  - LDS tile is float4 (x,y,z,|p|^2): sq computed ONCE per block in staging
//    (saves 5 VALU/pt/wave) and per-point LDS traffic is 1x ds_read_b128.
//  - all-VALU butterfly (permlane swaps instead of 2x ds_bpermute).
//  - winner-coord reads are software-pipelined: round r issues its sP[winj]
//    read and accumulates round r-1's coords under that latency, so the
//    16-round chain is butterfly+pop only (LDS latency off critical path).
// Keys k = (sortbits<<32)|j unique -> exact pop order == lax.top_k order;
// accumulation stays in ascending-distance order (bitwise-exact mean).
// ---------------------------------------------------------------------------
__global__ __launch_bounds__(TPB) void knn_gather_kernel(
    const float* __restrict__ pos, const float* __restrict__ vel,
    const float* __restrict__ phys, const float* __restrict__ refp,
    const int* __restrict__ anchors, float* __restrict__ out) {
    const int t = threadIdx.x;
    const int wid = t >> 6, lane = t & 63;
    const int g = blockIdx.x * 4 + wid;   // global anchor id (obj*64 + k)
    const int obj = g >> 6;

    __shared__ float4 sP[NPTS];           // (x,y,z,sq) per point, 32 KB
    const float* pts = pos + (size_t)obj * NPTS * 3;
    #pragma unroll
    for (int i = 0; i < FPT; i++) {
        const int j = t + i * TPB;
        const float x = pts[j * 3 + 0];
        const float y = pts[j * 3 + 1];
        const float z = pts[j * 3 + 2];
        sP[j] = make_float4(x, y, z, sq3(x, y, z));
    }
    const int a = anchors[g];   // global read, no LDS hazard
    __syncthreads();            // the only barrier

    const float4 ca = sP[a];
    const float ax = ca.x, ay = ca.y, az = ca.z;
    const float sqa = ca.w;     // identical bits to reference's sq[a]

    // d2 row exactly as reference: (sq_a + sq_j) - 2*dot, sign-flip sortable.
    u64 k[KPL];
    #pragma unroll
    for (int i = 0; i < KPL; i++) {
        const int j = lane + i * 64;
        const float4 p = sP[j];
        const float dot = __fadd_rn(
            __fadd_rn(__fmul_rn(ax, p.x), __fmul_rn(ay, p.y)), __fmul_rn(az, p.z));
        const float d2 = __fsub_rn(__fadd_rn(sqa, p.w), __fmul_rn(2.0f, dot));
        u32 bb = __float_as_uint(d2);
        bb ^= (bb & 0x80000000u) ? 0xFFFFFFFFu : 0x80000000u;
        k[i] = (j == a) ? UMAX : (((u64)bb << 32) | (u32)j);
    }

    // per-lane 4 smallest, ascending: c0 < c1 < c2 < c3 (keys unique)
    u64 c0 = UMAX, c1 = UMAX, c2 = UMAX, c3 = UMAX;
    #pragma unroll
    for (int i = 0; i < KPL; i++) c0 = (k[i] < c0) ? k[i] : c0;
    #pragma unroll
    for (int i = 0; i < KPL; i++) {
        const u64 v = (k[i] > c0) ? k[i] : UMAX; c1 = (v < c1) ? v : c1;
    }
    #pragma unroll
    for (int i = 0; i < KPL; i++) {
        const u64 v = (k[i] > c1) ? k[i] : UMAX; c2 = (v < c2) ? v : c2;
    }
    #pragma unroll
    for (int i = 0; i < KPL; i++) {
        const u64 v = (k[i] > c2) ? k[i] : UMAX; c3 = (v < c3) ? v : c3;
    }

    float accx = 0.f, accy = 0.f, accz = 0.f;
    u64 thr = 0;
    float4 cw;
    {
        // round 0: every lane has >=4 real candidates -> no refill possible
        const u64 w = wave_min64(c0);
        cw = sP[(int)(u32)w];              // issue read; consumed next round
        if (c0 == w) { thr = c0; c0 = c1; c1 = c2; c2 = c3; c3 = UMAX; }
    }
    #pragma unroll 1
    for (int r = 1; r < KNN; r++) {
        if (c0 == UMAX) {   // rare refill: 4 smallest keys > thr (c1..c3 UMAX here)
            #pragma unroll
            for (int i = 0; i < KPL; i++) {
                const u64 v = (k[i] > thr) ? k[i] : UMAX; c0 = (v < c0) ? v : c0;
            }
            #pragma unroll
            for (int i = 0; i < KPL; i++) {
                const u64 v = (k[i] > c0) ? k[i] : UMAX; c1 = (v < c1) ? v : c1;
            }
            #pragma unroll
            for (int i = 0; i < KPL; i++) {
                const u64 v = (k[i] > c1) ? k[i] : UMAX; c2 = (v < c2) ? v : c2;
            }
            #pragma unroll
            for (int i = 0; i < KPL; i++) {
                const u64 v = (k[i] > c2) ? k[i] : UMAX; c3 = (v < c3) ? v : c3;
            }
        }
        const u64 w = wave_min64(c0);       // global min; ties impossible
        const float4 cn = sP[(int)(u32)w];  // issue this round's read...
        // ...and accumulate LAST round's winner under its latency (exact order)
        accx = __fadd_rn(accx, __fsub_rn(cw.x, ax));
        accy = __fadd_rn(accy, __fsub_rn(cw.y, ay));
        accz = __fadd_rn(accz, __fsub_rn(cw.z, az));
        cw = cn;
        if (c0 == w) {                      // exactly one lane pops
            thr = c0; c0 = c1; c1 = c2; c2 = c3; c3 = UMAX;
        }
    }
    accx = __fadd_rn(accx, __fsub_rn(cw.x, ax));
    accy = __fadd_rn(accy, __fsub_rn(cw.y, ay));
    accz = __fadd_rn(accz, __fsub_rn(cw.z, az));

    if (lane == 0) {
        float* o = out + (size_t)g * 12;
        o[0] = __fmul_rn(accx, 0.0625f);   // /16 exact as *2^-4
        o[1] = __fmul_rn(accy, 0.0625f);
        o[2] = __fmul_rn(accz, 0.0625f);
        const size_t base = (size_t)obj * NPTS * 3 + (size_t)a * 3;
        o[3] = vel[base + 0];
        o[4] = vel[base + 1];
        o[5] = vel[base + 2];
        o[6] = __fsub_rn(pos[base + 0], refp[base + 0]);
        o[7] = __fsub_rn(pos[base + 1], refp[base + 1]);
        o[8] = __fsub_rn(pos[base + 2], refp[base + 2]);
        const float* ph = phys + (size_t)obj * 3;
        o[9]  = ph[0];
        o[10] = ph[1];
        o[11] = ph[2];
    }
}

extern "C" void kernel_launch(void* const* d_in, const int* in_sizes, int n_in,
                              void* d_out, int out_size, void* d_ws, size_t ws_size,
                              hipStream_t stream) {
    const float* pos  = (const float*)d_in[0];  // (4,8,2048,3)
    const float* vel  = (const float*)d_in[1];  // (4,8,2048,3)
    const float* phys = (const float*)d_in[2];  // (4,8,3)
    const float* refp = (const float*)d_in[3];  // (4,8,2048,3)
    float* out = (float*)d_out;                 // (4,8,64,12)

    const int n_obj = in_sizes[2] / 3;          // 32 objects
    int* anchors = (int*)d_ws;                  // n_obj * 64 ints

    fps_kernel<<<n_obj, 64, 0, stream>>>(pos, anchors);
    knn_gather_kernel<<<n_obj * AK / 4, TPB, 0, stream>>>(pos, vel, phys, refp,
                                                          anchors, out);
}

// Round 2
// 110.935 us; speedup vs baseline: 1.1364x; 1.1364x over previous
//
#include <hip/hip_runtime.h>
#include <stdint.h>

// Problem constants (fixed by setup_inputs: B=4, N_obj=8, N_v=2048)
#define NPTS 2048
#define KNN  16
#define AK   64
#define TPB  256
#define FPT  (NPTS / TPB)   // 8 points per thread (4-wave kernels)
#define KPL  (NPTS / 64)    // 32 points per lane (one wave per anchor)

typedef unsigned long long u64;
typedef unsigned int u32;
#define UMAX 0xFFFFFFFFFFFFFFFFull

// Exact float32 helpers (no FMA contraction -> match reference bitwise)
__device__ __forceinline__ float sq3(float x, float y, float z) {
    return __fadd_rn(__fadd_rn(__fmul_rn(x, x), __fmul_rn(y, y)), __fmul_rn(z, z));
}

// ---------------------------------------------------------------------------
// 64-lane butterfly reductions on u64 keys, ALL-VALU (no LDS/ds_bpermute).
// Stages 1,2,4,8: DPP permutations. quad_perm(1,0,3,2)=0xB1 is xor1;
// quad_perm(2,3,0,1)=0x4E is xor2; row_half_mirror(0x141)=xor4 once quads
// uniform; row_mirror(0x140)=xor8 once 8-groups uniform.
// Stages 16,32: gfx950 v_permlane16_swap / v_permlane32_swap with self;
// reducing with BOTH results realizes the xor exchange (self-compares are
// no-ops). Guarded by __has_builtin with shfl fallback. Correctness of this
// exact butterfly was harness-verified (absmax 0.0) in the previous round.
// ---------------------------------------------------------------------------
template <int CTRL>
__device__ __forceinline__ u64 dpp64(u64 k) {
    const int lo = __builtin_amdgcn_update_dpp((int)(u32)k, (int)(u32)k,
                                               CTRL, 0xF, 0xF, false);
    const int hi = __builtin_amdgcn_update_dpp((int)(u32)(k >> 32),
                                               (int)(u32)(k >> 32),
                                               CTRL, 0xF, 0xF, false);
    return ((u64)(u32)hi << 32) | (u32)lo;
}

__device__ __forceinline__ void swap16_pair(u64 k, u64& a, u64& b) {
#if __has_builtin(__builtin_amdgcn_permlane16_swap)
    const u32 lo = (u32)k, hi = (u32)(k >> 32);
    const auto rl = __builtin_amdgcn_permlane16_swap(lo, lo, false, false);
    const auto rh = __builtin_amdgcn_permlane16_swap(hi, hi, false, false);
    a = ((u64)(u32)rh[0] << 32) | (u32)rl[0];
    b = ((u64)(u32)rh[1] << 32) | (u32)rl[1];
#else
    a = (u64)__shfl_xor((long long)k, 16, 64);
    b = a;
#endif
}

__device__ __forceinline__ void swap32_pair(u64 k, u64& a, u64& b) {
#if __has_builtin(__builtin_amdgcn_permlane32_swap)
    const u32 lo = (u32)k, hi = (u32)(k >> 32);
    const auto rl = __builtin_amdgcn_permlane32_swap(lo, lo, false, false);
    const auto rh = __builtin_amdgcn_permlane32_swap(hi, hi, false, false);
    a = ((u64)(u32)rh[0] << 32) | (u32)rl[0];
    b = ((u64)(u32)rh[1] << 32) | (u32)rl[1];
#else
    a = (u64)__shfl_xor((long long)k, 32, 64);
    b = a;
#endif
}

__device__ __forceinline__ u64 wave_max64(u64 k) {
    u64 o, a, b;
    o = dpp64<0xB1>(k);  if (o > k) k = o;
    o = dpp64<0x4E>(k);  if (o > k) k = o;
    o = dpp64<0x141>(k); if (o > k) k = o;
    o = dpp64<0x140>(k); if (o > k) k = o;
    swap16_pair(k, a, b); if (a > k) k = a; if (b > k) k = b;
    swap32_pair(k, a, b); if (a > k) k = a; if (b > k) k = b;
    return k;
}

__device__ __forceinline__ u64 wave_min64(u64 k) {
    u64 o, a, b;
    o = dpp64<0xB1>(k);  if (o < k) k = o;
    o = dpp64<0x4E>(k);  if (o < k) k = o;
    o = dpp64<0x141>(k); if (o < k) k = o;
    o = dpp64<0x140>(k); if (o < k) k = o;
    swap16_pair(k, a, b); if (a < k) k = a; if (b < k) k = b;
    swap32_pair(k, a, b); if (a < k) k = a; if (b < k) k = b;
    return k;
}

// ---------------------------------------------------------------------------
// Kernel 1: farthest-point sampling, one block (4 waves) per object.
// Back to the 4-wave skeleton (FPT=8 -> 32 array VGPRs, zero spill; the
// 1-wave variant needed 128 array VGPRs and spilled, costing +15us).
// Step-path changes vs the 42.4us version:
//  - anchors buffered in LDS, ONE coalesced global store at the end. The
//    loop has no outstanding vmem, so __syncthreads' vmcnt(0) drain is free
//    (previously wave0 re-paid an L2 store round-trip per step).
//  - all-VALU butterfly (permlane swaps replace 2x ds_bpermute stages).
//  - float4 (x,y,z,0) point tile: lane0's winner-coord prefetch is a single
//    broadcast ds_read_b128 instead of 3 scalar reads.
// One barrier per step (double-buffered exchange slots; slot reuse is two
// barriers away -> race-free).
// ---------------------------------------------------------------------------
__global__ __launch_bounds__(TPB) void fps_kernel(const float* __restrict__ pos,
                                                  int* __restrict__ anchors) {
    const int obj = blockIdx.x;
    const int t = threadIdx.x;
    const int wid = t >> 6, lane = t & 63;

    __shared__ float4 sP[NPTS];  // (x,y,z,0) winner-lookup tile, 32 KB
    __shared__ u64 skey[8];      // double-buffered per-wave winner keys
    __shared__ float4 scrd[8];   // double-buffered per-wave winner coords
    __shared__ int sAnc[AK];     // anchor indices, flushed once at the end

    const float* pts = pos + (size_t)obj * NPTS * 3;
    float px[FPT], py[FPT], pz[FPT], mind[FPT];
    #pragma unroll
    for (int i = 0; i < FPT; i++) {
        const int j = t + i * TPB;
        const float x = pts[j * 3 + 0];
        const float y = pts[j * 3 + 1];
        const float z = pts[j * 3 + 2];
        px[i] = x; py[i] = y; pz[i] = z;
        sP[j] = make_float4(x, y, z, 0.f);
    }
    if (t == 0) sAnc[0] = 0;
    __syncthreads();

    u64 key;
    {
        const float4 c0 = sP[0];   // broadcast read
        float bv = -1.0f; u32 bj = 0;
        #pragma unroll
        for (int i = 0; i < FPT; i++) {
            const float d2 = sq3(__fsub_rn(px[i], c0.x), __fsub_rn(py[i], c0.y),
                                 __fsub_rn(pz[i], c0.z));
            mind[i] = d2;
            if (d2 > bv) { bv = d2; bj = (u32)(t + i * TPB); }  // strict: smallest j
        }
        // mind >= 0 -> float bits order-monotonic; ~j -> smaller j wins ties
        key = ((u64)__float_as_uint(bv) << 32) | (u32)(~bj);
    }

    #pragma unroll 1
    for (int s = 1; s < AK; s++) {
        const u64 wk = wave_max64(key);     // all lanes hold wave-winner
        const int side = (s & 1) * 4;
        if (lane == 0) {
            const int widx = (int)(~(u32)wk);
            skey[side + wid] = wk;
            scrd[side + wid] = sP[widx];    // 1x broadcast ds_read_b128
        }
        __syncthreads();   // only barrier per step; no vmem outstanding
        u64 ka = skey[side + 0];
        float4 ca = scrd[side + 0];
        { const u64 k1 = skey[side + 1]; const float4 q = scrd[side + 1];
          if (k1 > ka) { ka = k1; ca = q; } }
        { const u64 k2 = skey[side + 2]; const float4 q = scrd[side + 2];
          if (k2 > ka) { ka = k2; ca = q; } }
        { const u64 k3 = skey[side + 3]; const float4 q = scrd[side + 3];
          if (k3 > ka) { ka = k3; ca = q; } }
        if (t == 0) sAnc[s] = (int)(~(u32)ka);
        if (s == AK - 1) break;   // no update needed after last anchor

        // fused min-update + argmax scan (exact: direct (p-b)^2 like lax.scan)
        float bv = -1.0f; u32 bj = 0;
        #pragma unroll
        for (int i = 0; i < FPT; i++) {
            const float d2 = sq3(__fsub_rn(px[i], ca.x), __fsub_rn(py[i], ca.y),
                                 __fsub_rn(pz[i], ca.z));
            const float nm = fminf(mind[i], d2);
            mind[i] = nm;
            if (nm > bv) { bv = nm; bj = (u32)(t + i * TPB); }
        }
        key = ((u64)__float_as_uint(bv) << 32) | (u32)(~bj);
    }

    __syncthreads();
    if (t < AK) anchors[obj * AK + t] = sAnc[t];   // one coalesced store
}

// ---------------------------------------------------------------------------
// Kernel 2: KNN dist-vec + gather + concat. ONE WAVE per anchor, 4 anchors
// per block. (Unchanged from the harness-verified previous round.)
//  - LDS tile is float4 (x,y,z,|p|^2): sq computed ONCE per block in staging
//    and per-point LDS traffic is 1x ds_read_b128.
//  - all-VALU butterfly (permlane swaps instead of 2x ds_bpermute).
//  - winner-coord reads are software-pipelined: round r issues its sP[winj]
//    read and accumulates round r-1's coords under that latency.
// Keys k = (sortbits<<32)|j unique -> exact pop order == lax.top_k order;
// accumulation stays in ascending-distance order (bitwise-exact mean).
// ---------------------------------------------------------------------------
__global__ __launch_bounds__(TPB) void knn_gather_kernel(
    const float* __restrict__ pos, const float* __restrict__ vel,
    const float* __restrict__ phys, const float* __restrict__ refp,
    const int* __restrict__ anchors, float* __restrict__ out) {
    const int t = threadIdx.x;
    const int wid = t >> 6, lane = t & 63;
    const int g = blockIdx.x * 4 + wid;   // global anchor id (obj*64 + k)
    const int obj = g >> 6;

    __shared__ float4 sP[NPTS];           // (x,y,z,sq) per point, 32 KB
    const float* pts = pos + (size_t)obj * NPTS * 3;
    #pragma unroll
    for (int i = 0; i < FPT; i++) {
        const int j = t + i * TPB;
        const float x = pts[j * 3 + 0];
        const float y = pts[j * 3 + 1];
        const float z = pts[j * 3 + 2];
        sP[j] = make_float4(x, y, z, sq3(x, y, z));
    }
    const int a = anchors[g];   // global read, no LDS hazard
    __syncthreads();            // the only barrier

    const float4 ca = sP[a];
    const float ax = ca.x, ay = ca.y, az = ca.z;
    const float sqa = ca.w;     // identical bits to reference's sq[a]

    // d2 row exactly as reference: (sq_a + sq_j) - 2*dot, sign-flip sortable.
    u64 k[KPL];
    #pragma unroll
    for (int i = 0; i < KPL; i++) {
        const int j = lane + i * 64;
        const float4 p = sP[j];
        const float dot = __fadd_rn(
            __fadd_rn(__fmul_rn(ax, p.x), __fmul_rn(ay, p.y)), __fmul_rn(az, p.z));
        const float d2 = __fsub_rn(__fadd_rn(sqa, p.w), __fmul_rn(2.0f, dot));
        u32 bb = __float_as_uint(d2);
        bb ^= (bb & 0x80000000u) ? 0xFFFFFFFFu : 0x80000000u;
        k[i] = (j == a) ? UMAX : (((u64)bb << 32) | (u32)j);
    }

    // per-lane 4 smallest, ascending: c0 < c1 < c2 < c3 (keys unique)
    u64 c0 = UMAX, c1 = UMAX, c2 = UMAX, c3 = UMAX;
    #pragma unroll
    for (int i = 0; i < KPL; i++) c0 = (k[i] < c0) ? k[i] : c0;
    #pragma unroll
    for (int i = 0; i < KPL; i++) {
        const u64 v = (k[i] > c0) ? k[i] : UMAX; c1 = (v < c1) ? v : c1;
    }
    #pragma unroll
    for (int i = 0; i < KPL; i++) {
        const u64 v = (k[i] > c1) ? k[i] : UMAX; c2 = (v < c2) ? v : c2;
    }
    #pragma unroll
    for (int i = 0; i < KPL; i++) {
        const u64 v = (k[i] > c2) ? k[i] : UMAX; c3 = (v < c3) ? v : c3;
    }

    float accx = 0.f, accy = 0.f, accz = 0.f;
    u64 thr = 0;
    float4 cw;
    {
        // round 0: every lane has >=4 real candidates -> no refill possible
        const u64 w = wave_min64(c0);
        cw = sP[(int)(u32)w];              // issue read; consumed next round
        if (c0 == w) { thr = c0; c0 = c1; c1 = c2; c2 = c3; c3 = UMAX; }
    }
    #pragma unroll 1
    for (int r = 1; r < KNN; r++) {
        if (c0 == UMAX) {   // rare refill: 4 smallest keys > thr (c1..c3 UMAX here)
            #pragma unroll
            for (int i = 0; i < KPL; i++) {
                const u64 v = (k[i] > thr) ? k[i] : UMAX; c0 = (v < c0) ? v : c0;
            }
            #pragma unroll
            for (int i = 0; i < KPL; i++) {
                const u64 v = (k[i] > c0) ? k[i] : UMAX; c1 = (v < c1) ? v : c1;
            }
            #pragma unroll
            for (int i = 0; i < KPL; i++) {
                const u64 v = (k[i] > c1) ? k[i] : UMAX; c2 = (v < c2) ? v : c2;
            }
            #pragma unroll
            for (int i = 0; i < KPL; i++) {
                const u64 v = (k[i] > c2) ? k[i] : UMAX; c3 = (v < c3) ? v : c3;
            }
        }
        const u64 w = wave_min64(c0);       // global min; ties impossible
        const float4 cn = sP[(int)(u32)w];  // issue this round's read...
        // ...and accumulate LAST round's winner under its latency (exact order)
        accx = __fadd_rn(accx, __fsub_rn(cw.x, ax));
        accy = __fadd_rn(accy, __fsub_rn(cw.y, ay));
        accz = __fadd_rn(accz, __fsub_rn(cw.z, az));
        cw = cn;
        if (c0 == w) {                      // exactly one lane pops
            thr = c0; c0 = c1; c1 = c2; c2 = c3; c3 = UMAX;
        }
    }
    accx = __fadd_rn(accx, __fsub_rn(cw.x, ax));
    accy = __fadd_rn(accy, __fsub_rn(cw.y, ay));
    accz = __fadd_rn(accz, __fsub_rn(cw.z, az));

    if (lane == 0) {
        float* o = out + (size_t)g * 12;
        o[0] = __fmul_rn(accx, 0.0625f);   // /16 exact as *2^-4
        o[1] = __fmul_rn(accy, 0.0625f);
        o[2] = __fmul_rn(accz, 0.0625f);
        const size_t base = (size_t)obj * NPTS * 3 + (size_t)a * 3;
        o[3] = vel[base + 0];
        o[4] = vel[base + 1];
        o[5] = vel[base + 2];
        o[6] = __fsub_rn(pos[base + 0], refp[base + 0]);
        o[7] = __fsub_rn(pos[base + 1], refp[base + 1]);
        o[8] = __fsub_rn(pos[base + 2], refp[base + 2]);
        const float* ph = phys + (size_t)obj * 3;
        o[9]  = ph[0];
        o[10] = ph[1];
        o[11] = ph[2];
    }
}

extern "C" void kernel_launch(void* const* d_in, const int* in_sizes, int n_in,
                              void* d_out, int out_size, void* d_ws, size_t ws_size,
                              hipStream_t stream) {
    const float* pos  = (const float*)d_in[0];  // (4,8,2048,3)
    const float* vel  = (const float*)d_in[1];  // (4,8,2048,3)
    const float* phys = (const float*)d_in[2];  // (4,8,3)
    const float* refp = (const float*)d_in[3];  // (4,8,2048,3)
    float* out = (float*)d_out;                 // (4,8,64,12)

    const int n_obj = in_sizes[2] / 3;          // 32 objects
    int* anchors = (int*)d_ws;                  // n_obj * 64 ints

    fps_kernel<<<n_obj, TPB, 0, stream>>>(pos, anchors);
    knn_gather_kernel<<<n_obj * AK / 4, TPB, 0, stream>>>(pos, vel, phys, refp,
                                                          anchors, out);
}